// Round 3
// baseline (542.366 us; speedup 1.0000x reference)
//
#include <hip/hip_runtime.h>
#include <hip/hip_bf16.h>

// B=4, S=2048, D=512. fp32 in/out, bf16 MFMA internals.
// Key identity: multiplicative causal mask => E = 1 + F, F = expm1(scale*s) on
// the lower triangle (q>=k), 0 above. Then
//   out  = F @ vp'  +  T,   T[b,d] = sum_k vp'[b,k,d]
//   Z[k] = 2048 + colsum(F)
// so the scores GEMM runs only lower-triangular tiles (53%) and the out GEMM
// truncates K at m0+64 (52%).
//
// R3: ONE persistent kernel (768 blocks, 48 KB LDS, 3 blocks/CU co-resident)
//     with a hand-rolled device-scope grid barrier (monotone counter in
//     d_out[0], __threadfence release/acquire, bounded spin). Phases:
//     cvt+ZF0 | proj(768 tiles) | scoresF(544) | scale(2048 rows) | outF(512).
//     Removes ~6 launch/drain boundaries + memset launch.
//     Barrier idiom switched to the proven m201 form: __builtin s_barrier +
//     clobber-free s_waitcnt vmcnt(N) + sched_barrier(0) pin (the old
//     asm-"memory"-clobber form risks a compiler-inserted vmcnt(0) drain per
//     iteration). outF rebuilt at BK=32 (3 bufs x 12 KB = 36 KB) to fit the
//     shared 48 KB LDS footprint.

#define S_LEN 2048
#define D_DIM 512
#define SCALE_F 0.044194173824159216f  // 1/sqrt(512)
#define NBLK 768

typedef __attribute__((ext_vector_type(8))) short s8v;   // 8 bf16 = 4 VGPRs
typedef __attribute__((ext_vector_type(4))) short s4v;   // 4 bf16 = 8 B
typedef __attribute__((ext_vector_type(4))) float f4v;   // MFMA accumulator

enum { EPI_BIAS = 0, EPI_BIAS_T = 1, EPI_SCORES = 2 };

#define SBAR()    __builtin_amdgcn_s_barrier()
#define SCHEDB()  __builtin_amdgcn_sched_barrier(0)
#define WAITV(n)  asm volatile("s_waitcnt vmcnt(" #n ")")

__device__ __forceinline__ short f2bf_s(float f) {
  union { __hip_bfloat16 b; short s; } u; u.b = __float2bfloat16(f); return u.s;
}
__device__ __forceinline__ float bf2f_s(short h) {
  union { short s; __hip_bfloat16 b; } u; u.s = h; return __bfloat162float(u.b);
}

__device__ __forceinline__ void glds16(const short* g, short* l) {
  __builtin_amdgcn_global_load_lds((const __attribute__((address_space(1))) void*)g,
                                   (__attribute__((address_space(3))) void*)l, 16, 0, 0);
}

// Device-scope grid barrier: monotone counter, all NBLK blocks co-resident.
// Release: __threadfence before add (flushes this XCD's L2). Acquire:
// __threadfence after spin (invalidates L0/L2 clean lines). Bounded spin so a
// broken barrier fails verification instead of hanging.
__device__ __forceinline__ void gsync(int* bar, int target) {
  __syncthreads();
  if (threadIdx.x == 0) {
    __threadfence();
    __hip_atomic_fetch_add(bar, 1, __ATOMIC_RELAXED, __HIP_MEMORY_SCOPE_AGENT);
    int guard = 0;
    while (__hip_atomic_load(bar, __ATOMIC_RELAXED, __HIP_MEMORY_SCOPE_AGENT) < target) {
      __builtin_amdgcn_s_sleep(1);
      if (++guard > (1 << 27)) break;
    }
    __threadfence();
  }
  __syncthreads();
}

// Core NT GEMM, 128x128 tile at (m0,n0), BK=32, 3-deep LDS pipeline (48 KB).
// SMEM: buf b at b*8192 shorts; As=+0 (128x32), Bs=+4096 (128x32).
// Per iter: WAITV(tile i ready, counted) -> s_barrier -> sched fence ->
// issue tile i+2 -> ds_read -> 16 MFMA. Loads stay in flight across barriers.
template <int EPI>
__device__ __forceinline__ void gemm_core(
    const short* __restrict__ A, const short* __restrict__ B,
    short* __restrict__ C, const float* __restrict__ bias,
    short* SMEM, int N, int K, size_t sCz, int m0, int n0, int bz,
    float* __restrict__ Z)
{
  const int tid  = threadIdx.x;
  const int w    = tid >> 6;
  const int lane = tid & 63;
  const int quad = lane >> 4;
  const int l16  = lane & 15;
  const int wm   = (w >> 1) * 64;
  const int wn   = (w & 1) * 64;

  const int strow = tid >> 2;                         // 0..63 (row, 2 rounds)
  const int gl = ((tid & 3) ^ (strow & 3)) * 8;       // XOR column-octet swizzle

  f4v acc[4][4];
#pragma unroll
  for (int i = 0; i < 4; ++i)
#pragma unroll
    for (int j = 0; j < 4; ++j)
#pragma unroll
      for (int r = 0; r < 4; ++r) acc[i][j][r] = 0.0f;

  const short* Ag = A + (size_t)(m0 + strow) * K + gl;
  const short* Bg = B + (size_t)(n0 + strow) * K + gl;
  const size_t pstr = (size_t)64 * K;
  const int t8 = tid * 8;
  const int swq = l16 & 3;

  const int niter = K >> 5;   // >= 2 for all callers

  // preload tiles 0,1 -> bufs 0,1 (4 loads each)
#pragma unroll
  for (int t = 0; t < 2; ++t) {
    const int k0 = t << 5;
    short* dst = SMEM + t * 8192 + t8;
#pragma unroll
    for (int p = 0; p < 2; ++p) glds16(Ag + k0 + p * pstr, dst + p * 2048);
#pragma unroll
    for (int p = 0; p < 2; ++p) glds16(Bg + k0 + p * pstr, dst + 4096 + p * 2048);
  }

  int cb = 0;   // buffer holding tile i
  for (int i = 0; i < niter; ++i) {
    if (i + 1 < niter) { WAITV(4); } else { WAITV(0); }
    SBAR();
    SCHEDB();   // nothing (prefetch/ds_read) may hoist above the barrier

    if (i + 2 < niter) {
      int nb = cb + 2; if (nb >= 3) nb -= 3;
      const int k2 = (i + 2) << 5;
      short* dst = SMEM + nb * 8192 + t8;
#pragma unroll
      for (int p = 0; p < 2; ++p) glds16(Ag + k2 + p * pstr, dst + p * 2048);
#pragma unroll
      for (int p = 0; p < 2; ++p) glds16(Bg + k2 + p * pstr, dst + 4096 + p * 2048);
    }

    const short* As = SMEM + cb * 8192;
    const short* Bs = As + 4096;
    cb = (cb == 2) ? 0 : cb + 1;

    s8v af[4], bf[4];
#pragma unroll
    for (int ii = 0; ii < 4; ++ii)
      af[ii] = *(const s8v*)&As[(wm + ii * 16 + l16) * 32 + ((quad ^ swq) * 8)];
#pragma unroll
    for (int j = 0; j < 4; ++j)
      bf[j] = *(const s8v*)&Bs[(wn + j * 16 + l16) * 32 + ((quad ^ swq) * 8)];
#pragma unroll
    for (int ii = 0; ii < 4; ++ii)
#pragma unroll
      for (int j = 0; j < 4; ++j)
        acc[ii][j] = __builtin_amdgcn_mfma_f32_16x16x32_bf16(af[ii], bf[j], acc[ii][j], 0, 0, 0);
  }

  // ---- epilogue ----
  float bv[4];
  if (EPI == EPI_BIAS || EPI == EPI_BIAS_T) {
#pragma unroll
    for (int j = 0; j < 4; ++j) bv[j] = bias[n0 + wn + j * 16 + l16];
  }

  if (EPI == EPI_BIAS_T) {
#pragma unroll
    for (int i = 0; i < 4; ++i) {
#pragma unroll
      for (int j = 0; j < 4; ++j) {
        const int gn  = n0 + wn + j * 16 + l16;
        const int gmb = m0 + wm + i * 16 + quad * 4;
        const int bb = gmb >> 11, ssb = gmb & (S_LEN - 1);
        s4v o;
#pragma unroll
        for (int r = 0; r < 4; ++r) o[r] = f2bf_s(acc[i][j][r] + bv[j]);
        *(s4v*)&C[((size_t)bb * D_DIM + gn) * S_LEN + ssb] = o;
      }
    }
    return;
  }

  // EPI_BIAS / EPI_SCORES: LDS transpose -> coalesced 16B row stores.
  short* TB = SMEM;                 // 4 waves x 2176 shorts (32 rows x stride 68)
  const int wbase = w * 2176;
  float csum[4] = {0.f, 0.f, 0.f, 0.f};

#pragma unroll
  for (int ph = 0; ph < 2; ++ph) {
    __syncthreads();
#pragma unroll
    for (int ii = 0; ii < 2; ++ii) {
      const int i = ph * 2 + ii;
#pragma unroll
      for (int j = 0; j < 4; ++j) {
        const int gn = n0 + wn + j * 16 + l16;
#pragma unroll
        for (int r = 0; r < 4; ++r) {
          short o;
          if (EPI == EPI_SCORES) {
            const int gm = m0 + wm + i * 16 + quad * 4 + r;
            const float f = (gm >= gn) ? (__expf(acc[i][j][r] * SCALE_F) - 1.0f) : 0.0f;
            csum[j] += f;
            o = f2bf_s(f);
          } else {
            o = f2bf_s(acc[i][j][r] + bv[j]);
          }
          TB[wbase + (ii * 16 + quad * 4 + r) * 68 + j * 16 + l16] = o;
        }
      }
    }
    __syncthreads();
#pragma unroll
    for (int p = 0; p < 4; ++p) {
      const int row = p * 8 + (lane >> 3);   // 0..31
      const int cg  = lane & 7;
      const s8v vv = *(const s8v*)&TB[wbase + row * 68 + cg * 8];
      const int gm = m0 + wm + ph * 32 + row;
      const int gn = n0 + wn + cg * 8;
      *(s8v*)&C[sCz + (size_t)gm * N + gn] = vv;
    }
  }

  if (EPI == EPI_SCORES) {
#pragma unroll
    for (int j = 0; j < 4; ++j) {
      float cs = csum[j];
      cs += __shfl_xor(cs, 16, 64);
      cs += __shfl_xor(cs, 32, 64);
      if (quad == 0) atomicAdd(&Z[(bz << 11) + n0 + wn + j * 16 + l16], cs);
    }
  }
}

// out = F @ vpT'^T + T, 64x128 tile, BK=32, 3-deep pipeline (36 KB of SMEM).
// SMEM: buf c at c*6144 shorts; As=+0 (64x32), Bs=+2048 (128x32).
__device__ __forceinline__ void outF_body(
    const short* __restrict__ F, const short* __restrict__ vpT,
    const float* __restrict__ Tv, float* __restrict__ out,
    int bz, int zs, int n0, short* SMEM)
{
  const int tid  = threadIdx.x;
  const int mi   = (zs < 16) ? (31 - zs) : (zs - 16);  // niter = 2(mi+1); long first
  const int m0   = mi * 64;

  const short* A = F   + (size_t)bz * S_LEN * S_LEN;
  const short* B = vpT + (size_t)bz * D_DIM * S_LEN;

  const int w    = tid >> 6;
  const int lane = tid & 63;
  const int quad = lane >> 4;
  const int l16  = lane & 15;
  const int wm   = (w >> 1) * 32;
  const int wn   = (w & 1) * 64;

  const int strow = tid >> 2;                      // 0..63
  const int gl = ((tid & 3) ^ (strow & 3)) * 8;

  f4v acc[2][4];
#pragma unroll
  for (int i = 0; i < 2; ++i)
#pragma unroll
    for (int j = 0; j < 4; ++j)
#pragma unroll
      for (int r = 0; r < 4; ++r) acc[i][j][r] = 0.0f;

  const short* Ag = A + (size_t)(m0 + strow) * S_LEN + gl;
  const short* Bg = B + (size_t)(n0 + strow) * S_LEN + gl;
  const size_t pstr = (size_t)64 * S_LEN;
  const int t8 = tid * 8;
  const int swq = l16 & 3;

  const int niter = (m0 + 64) >> 5;   // K runs 0 .. m0+64, 2..64 iters

  // preload tiles 0,1 -> bufs 0,1 (3 loads each: A x1, B x2)
#pragma unroll
  for (int pre = 0; pre < 2; ++pre) {
    short* dst = SMEM + pre * 6144 + t8;
    const int k0 = pre << 5;
    glds16(Ag + k0, dst);
#pragma unroll
    for (int p = 0; p < 2; ++p) glds16(Bg + k0 + p * pstr, dst + 2048 + p * 2048);
  }

  int cb = 0;
  for (int i = 0; i < niter; ++i) {
    if (i + 1 < niter) { WAITV(3); } else { WAITV(0); }
    SBAR();
    SCHEDB();

    if (i + 2 < niter) {
      int nb = cb + 2; if (nb >= 3) nb -= 3;
      const int k2 = (i + 2) << 5;
      short* dst = SMEM + nb * 6144 + t8;
      glds16(Ag + k2, dst);
#pragma unroll
      for (int p = 0; p < 2; ++p) glds16(Bg + k2 + p * pstr, dst + 2048 + p * 2048);
    }

    const short* As = SMEM + cb * 6144;
    const short* Bs = As + 2048;
    cb = (cb == 2) ? 0 : cb + 1;

    s8v af[2], bf[4];
#pragma unroll
    for (int ii = 0; ii < 2; ++ii)
      af[ii] = *(const s8v*)&As[(wm + ii * 16 + l16) * 32 + ((quad ^ swq) * 8)];
#pragma unroll
    for (int j = 0; j < 4; ++j)
      bf[j] = *(const s8v*)&Bs[(wn + j * 16 + l16) * 32 + ((quad ^ swq) * 8)];
#pragma unroll
    for (int ii = 0; ii < 2; ++ii)
#pragma unroll
      for (int j = 0; j < 4; ++j)
        acc[ii][j] = __builtin_amdgcn_mfma_f32_16x16x32_bf16(af[ii], bf[j], acc[ii][j], 0, 0, 0);
  }

  float* Cf = out + (size_t)bz * S_LEN * D_DIM;
#pragma unroll
  for (int i = 0; i < 2; ++i) {
#pragma unroll
    for (int j = 0; j < 4; ++j) {
      const int gn = n0 + wn + j * 16 + l16;
      const float tvn = Tv[(bz << 9) + gn];
#pragma unroll
      for (int r = 0; r < 4; ++r) {
        const int gm = m0 + wm + i * 16 + quad * 4 + r;
        Cf[(size_t)gm * D_DIM + gn] = acc[i][j][r] + tvn;
      }
    }
  }
}

// ---------------- the single persistent kernel ----------------
__global__ __launch_bounds__(256, 3) void fused_all(
    const float* __restrict__ q, const float* __restrict__ k, const float* __restrict__ v,
    const float* __restrict__ WQw, const float* __restrict__ WQb,
    const float* __restrict__ WKw, const float* __restrict__ WKb,
    const float* __restrict__ WVw, const float* __restrict__ WVb,
    char* __restrict__ ws, float* __restrict__ out, int* __restrict__ bar)
{
  __shared__ __align__(16) short SMEM[24576];   // 48 KB
  __shared__ float red2[4];

  const int bid = blockIdx.x;
  const int tid = threadIdx.x;
  const int tg  = bid * 256 + tid;              // 0..196607

  // workspace layout (F aliases the bf16 input/weight slabs, dead before F)
  short* qb  = (short*)(ws);                 // 24 MB  (qb,kb,vb contiguous)
  short* Wqb = (short*)(ws + 25165824);      // 3x 512 KB contiguous
  short* qp  = (short*)(ws + 33554432);      //  8 MB  [4][2048][512]
  short* kp  = (short*)(ws + 41943040);      //  8 MB
  short* vpT = (short*)(ws + 50331648);      //  8 MB  [4][512][2048]
  float* ZF  = (float*)(ws + 58720256);      // 32 KB  [4][2048]
  float* Tv  = (float*)(ws + 58753024);      //  8 KB  [4][512]
  short* F   = (short*)(ws);                 // 32 MB  [4][2048][2048] lower tiles
  short* kb  = qb + 4194304;
  short* vb  = qb + 8388608;
  short* Wkb = Wqb + 262144;
  short* Wvb = Wqb + 524288;

  // ---- phase 0: fp32->bf16 conversions + ZF zero ----
  {
#pragma unroll 2
    for (int it = 0; it < 8; ++it) {
      const int e = (it * 196608 + tg) * 8;            // < 12582912
      const float* s; int off;
      if (e < 4194304)       { s = q; off = e; }
      else if (e < 8388608)  { s = k; off = e - 4194304; }
      else                   { s = v; off = e - 8388608; }
      const float4 f0 = *(const float4*)(s + off);
      const float4 f1 = *(const float4*)(s + off + 4);
      s8v o;
      o[0] = f2bf_s(f0.x); o[1] = f2bf_s(f0.y); o[2] = f2bf_s(f0.z); o[3] = f2bf_s(f0.w);
      o[4] = f2bf_s(f1.x); o[5] = f2bf_s(f1.y); o[6] = f2bf_s(f1.z); o[7] = f2bf_s(f1.w);
      *(s8v*)(qb + e) = o;
    }
    if (tg < 98304) {
      const int e = tg * 8;                            // < 786432
      const float* s; int off;
      if (e < 262144)        { s = WQw; off = e; }
      else if (e < 524288)   { s = WKw; off = e - 262144; }
      else                   { s = WVw; off = e - 524288; }
      const float4 f0 = *(const float4*)(s + off);
      const float4 f1 = *(const float4*)(s + off + 4);
      s8v o;
      o[0] = f2bf_s(f0.x); o[1] = f2bf_s(f0.y); o[2] = f2bf_s(f0.z); o[3] = f2bf_s(f0.w);
      o[4] = f2bf_s(f1.x); o[5] = f2bf_s(f1.y); o[6] = f2bf_s(f1.z); o[7] = f2bf_s(f1.w);
      *(s8v*)((short*)Wqb + e) = o;
    }
    if (tg < 8192) ZF[tg] = 0.0f;
  }
  gsync(bar, NBLK);

  // ---- phase 1: projections (768 tiles: z = bid>>8, m,n from bid&255) ----
  {
    const int z   = bid >> 8;
    const int rem = bid & 255;
    const int n0  = (rem & 3) * 128;
    const int m0  = (rem >> 2) * 128;
    const short* A = (z == 0) ? qb : (z == 1) ? kb : vb;
    const short* B = (z == 0) ? Wqb : (z == 1) ? Wkb : Wvb;
    short*       C = (z == 0) ? qp : (z == 1) ? kp : vpT;
    const float* bias = (z == 0) ? WQb : (z == 1) ? WKb : WVb;
    if (z == 2)
      gemm_core<EPI_BIAS_T>(A, B, C, bias, SMEM, D_DIM, D_DIM, 0, m0, n0, 0, nullptr);
    else
      gemm_core<EPI_BIAS>(A, B, C, bias, SMEM, D_DIM, D_DIM, 0, m0, n0, 0, nullptr);
  }
  gsync(bar, 2 * NBLK);

  // ---- phase 2: F = expm1(scale*qp@kp^T) lower-tri tiles + ZF colsum ----
  if (bid < 544) {
    const int bz = bid / 136;
    const int t  = bid - bz * 136;
    int ti = (int)((sqrtf(8.0f * t + 1.0f) - 1.0f) * 0.5f);
    while ((ti + 1) * (ti + 2) / 2 <= t) ++ti;
    while (ti * (ti + 1) / 2 > t) --ti;
    const int tj = t - ti * (ti + 1) / 2;       // tj <= ti
    gemm_core<EPI_SCORES>(qp + (size_t)bz * S_LEN * D_DIM, kp + (size_t)bz * S_LEN * D_DIM,
                          F, nullptr, SMEM, S_LEN, D_DIM,
                          (size_t)bz * S_LEN * S_LEN, ti * 128, tj * 128, bz, ZF);
  }
  gsync(bar, 3 * NBLK);

  // ---- phase 3: vpT /= (2048+ZF); Tv = rowsum (2048 row-tasks) ----
  for (int r = bid; r < 2048; r += NBLK) {
    __syncthreads();
    const int b = r >> 9, d = r & 511;
    const size_t rowbase = ((size_t)(b * D_DIM + d)) * S_LEN;
    const float* zf = ZF + (b << 11);
    const int k0 = tid * 8;
    s8v vv = *(s8v*)&vpT[rowbase + k0];
    float s = 0.0f;
#pragma unroll
    for (int i = 0; i < 8; ++i) {
      const float wgt = bf2f_s(vv[i]) / (2048.0f + zf[k0 + i]);
      s += wgt;
      vv[i] = f2bf_s(wgt);
    }
    *(s8v*)&vpT[rowbase + k0] = vv;
#pragma unroll
    for (int off = 32; off >= 1; off >>= 1) s += __shfl_xor(s, off, 64);
    if ((tid & 63) == 0) red2[tid >> 6] = s;
    __syncthreads();
    if (tid == 0) Tv[(b << 9) + d] = red2[0] + red2[1] + red2[2] + red2[3];
  }
  gsync(bar, 4 * NBLK);

  // ---- phase 4: out = F @ vpT'^T + Tv (512 tiles, CU-balanced pairs) ----
  if (bid < 512) {
    const int n0 = (bid & 3) * 128;
    const int bz = (bid >> 2) & 3;
    const int zs = bid >> 4;              // 0..31
    outF_body(F, vpT, Tv, out, bz, zs, n0, SMEM);
  }
}

extern "C" void kernel_launch(void* const* d_in, const int* in_sizes, int n_in,
                              void* d_out, int out_size, void* d_ws, size_t ws_size,
                              hipStream_t stream) {
  const float* q   = (const float*)d_in[0];
  const float* k   = (const float*)d_in[1];
  const float* v   = (const float*)d_in[2];
  const float* WQw = (const float*)d_in[3];
  const float* WQb = (const float*)d_in[4];
  const float* WKw = (const float*)d_in[5];
  const float* WKb = (const float*)d_in[6];
  const float* WVw = (const float*)d_in[7];
  const float* WVb = (const float*)d_in[8];

  // grid-barrier counter lives in d_out[0..15] (out is fully rewritten by
  // phase 4, after the last sync)
  int* bar = (int*)d_out;
  hipMemsetAsync(bar, 0, 64, stream);

  fused_all<<<dim3(NBLK), dim3(256), 0, stream>>>(
      q, k, v, WQw, WQb, WKw, WKb, WVw, WVb,
      (char*)d_ws, (float*)d_out, bar);
}

// Round 5
// 168.498 us; speedup vs baseline: 3.2188x; 3.2188x over previous
//
#include <hip/hip_runtime.h>
#include <hip/hip_bf16.h>

// B=4, S=2048, D=512. fp32 in/out, bf16 MFMA internals.
// Key identity: multiplicative causal mask => E = 1 + F, F = expm1(scale*s) on
// the lower triangle (q>=k), 0 above. Then
//   out  = F @ vp'  +  T,   T[b,d] = sum_k vp'[b,k,d]
//   Z[k] = 2048 + colsum(F)
// Pipeline: cvt_all | proj3 | scoresF | scaleT | outF   (multi-kernel; R3's
// persistent-fusion grid barrier cost ~300us and is reverted).
//
// R4b: compile fix only (local swizzle id renamed bsw; it collided with the
//     b2 pointer parameter in proj3). Structure as R4:
//     BK=64 conflict-free swizzle; K-loop per T3/T4/T5: inline-asm
//     ds_read_b128 + explicit lgkmcnt(0) + sched_barrier(0) (rule 18), two
//     phases per K-step with s_setprio(1) around each MFMA cluster;
//     XCD-bijective block swizzle on proj3 (768=8x96) and scoresF (544=8x68);
//     cvt merged into one launch; outF BK=64 triple-buffer, prefetch issued
//     AFTER the barrier, balanced complementary niter pairing.

#define S_LEN 2048
#define D_DIM 512
#define SCALE_F 0.044194173824159216f  // 1/sqrt(512)

typedef __attribute__((ext_vector_type(8))) short s8v;   // 8 bf16 = 4 VGPRs
typedef __attribute__((ext_vector_type(4))) short s4v;   // 4 bf16 = 8 B
typedef __attribute__((ext_vector_type(4))) float f4v;   // MFMA accumulator

enum { EPI_BIAS = 0, EPI_BIAS_T = 1, EPI_SCORES = 2 };

#define SBAR()    __builtin_amdgcn_s_barrier()
#define SCHEDB()  __builtin_amdgcn_sched_barrier(0)
#define WAITV(n)  asm volatile("s_waitcnt vmcnt(" #n ")")
#define WAITL0()  asm volatile("s_waitcnt lgkmcnt(0)")

__device__ __forceinline__ short f2bf_s(float f) {
  union { __hip_bfloat16 b; short s; } u; u.b = __float2bfloat16(f); return u.s;
}
__device__ __forceinline__ float bf2f_s(short h) {
  union { short s; __hip_bfloat16 b; } u; u.s = h; return __bfloat162float(u.b);
}

__device__ __forceinline__ void glds16(const short* g, short* l) {
  __builtin_amdgcn_global_load_lds((const __attribute__((address_space(1))) void*)g,
                                   (__attribute__((address_space(3))) void*)l, 16, 0, 0);
}

// LDS byte offset of a __shared__-derived pointer (addrspace(3) is 32-bit).
__device__ __forceinline__ unsigned lds_addr(const short* p) {
  return (unsigned)(unsigned long long)(const __attribute__((address_space(3))) short*)p;
}

// Inline-asm ds_read_b128: invisible to the waitcnt pass, so the counted
// WAITV above stays authoritative. MUST be followed by lgkmcnt(0)+SCHEDB
// before any consumer (rule 18).
__device__ __forceinline__ s8v dsr128(unsigned a) {
  s8v r;
  asm volatile("ds_read_b128 %0, %1" : "=&v"(r) : "v"(a));
  return r;
}

// Core NT GEMM, 128x128 tile at (m0,n0), BK=64, double-buffered LDS (64 KB).
// SMEM: buf c at byte c*32768; As=+0 (128 rows x 128 B), Bs=+16384.
// Per iter: prefetch i+1 (safe: buf 1-c fenced by prior end-barrier) ->
// WAITV(8) -> SBAR -> 2 phases of {8 asm ds_read, lgkmcnt(0), sched fence,
// setprio(1), 16 MFMA, setprio(0)} -> SBAR.
template <int EPI>
__device__ __forceinline__ void gemm_core(
    const short* __restrict__ A, const short* __restrict__ B,
    short* __restrict__ C, const float* __restrict__ bias,
    short* SMEM, int N, int K, size_t sCz, int m0, int n0, int bz,
    float* __restrict__ Z)
{
  const int tid  = threadIdx.x;
  const int w    = tid >> 6;
  const int lane = tid & 63;
  const int quad = lane >> 4;
  const int l16  = lane & 15;
  const int wm   = (w >> 1) * 64;
  const int wn   = (w & 1) * 64;

  const int strow = tid >> 3;                         // 0..31
  const int gl = ((tid & 7) ^ (strow & 7)) * 8;       // XOR column-octet swizzle

  f4v acc[4][4];
#pragma unroll
  for (int i = 0; i < 4; ++i)
#pragma unroll
    for (int j = 0; j < 4; ++j)
#pragma unroll
      for (int r = 0; r < 4; ++r) acc[i][j][r] = 0.0f;

  const short* Ag = A + (size_t)(m0 + strow) * K + gl;
  const short* Bg = B + (size_t)(n0 + strow) * K + gl;
  const size_t pstr = (size_t)32 * K;
  const int t8 = tid * 8;
  const int swq = l16 & 7;

  // per-thread LDS byte addresses for fragment reads (buf0, kk=0);
  // kk=1 is addr^64.
  const unsigned base = lds_addr(SMEM);
  unsigned aoff[4], boff[4];
#pragma unroll
  for (int ii = 0; ii < 4; ++ii)
    aoff[ii] = base + (unsigned)((wm + ii * 16 + l16) * 128 + ((quad ^ swq) * 16));
#pragma unroll
  for (int j = 0; j < 4; ++j)
    boff[j] = base + 16384u + (unsigned)((wn + j * 16 + l16) * 128 + ((quad ^ swq) * 16));

  const int niter = K >> 6;

  // prologue: tile0 -> buf0 (8 loads/wave)
#pragma unroll
  for (int p = 0; p < 4; ++p) glds16(Ag + p * pstr, SMEM + t8 + p * 2048);
#pragma unroll
  for (int p = 0; p < 4; ++p) glds16(Bg + p * pstr, SMEM + 8192 + t8 + p * 2048);

  for (int i = 0; i < niter; ++i) {
    const int c = i & 1;
    if (i + 1 < niter) {
      const int k1 = (i + 1) << 6;
      short* dA = SMEM + (1 - c) * 16384 + t8;
#pragma unroll
      for (int p = 0; p < 4; ++p) glds16(Ag + k1 + p * pstr, dA + p * 2048);
#pragma unroll
      for (int p = 0; p < 4; ++p) glds16(Bg + k1 + p * pstr, dA + 8192 + p * 2048);
      SCHEDB();
      WAITV(8);          // tile i landed; tile i+1's 8 stay in flight
    } else {
      WAITV(0);
    }
    SBAR();
    SCHEDB();

    const unsigned cofs = (unsigned)(c << 15);
#pragma unroll
    for (int kk = 0; kk < 2; ++kk) {
      const unsigned kx = (unsigned)(kk << 6);
      s8v af[4], bf[4];
#pragma unroll
      for (int ii = 0; ii < 4; ++ii) af[ii] = dsr128((aoff[ii] ^ kx) + cofs);
#pragma unroll
      for (int j = 0; j < 4; ++j)   bf[j]  = dsr128((boff[j] ^ kx) + cofs);
      WAITL0();
      SCHEDB();
      __builtin_amdgcn_s_setprio(1);
#pragma unroll
      for (int ii = 0; ii < 4; ++ii)
#pragma unroll
        for (int j = 0; j < 4; ++j)
          acc[ii][j] = __builtin_amdgcn_mfma_f32_16x16x32_bf16(af[ii], bf[j], acc[ii][j], 0, 0, 0);
      __builtin_amdgcn_s_setprio(0);
    }
    SBAR();              // buf c free for next iter's prefetch
  }

  // ---- epilogue ----
  float bv[4];
  if (EPI == EPI_BIAS || EPI == EPI_BIAS_T) {
#pragma unroll
    for (int j = 0; j < 4; ++j) bv[j] = bias[n0 + wn + j * 16 + l16];
  }

  if (EPI == EPI_BIAS_T) {
#pragma unroll
    for (int i = 0; i < 4; ++i) {
#pragma unroll
      for (int j = 0; j < 4; ++j) {
        const int gn  = n0 + wn + j * 16 + l16;
        const int gmb = m0 + wm + i * 16 + quad * 4;
        const int bb = gmb >> 11, ssb = gmb & (S_LEN - 1);
        s4v o;
#pragma unroll
        for (int r = 0; r < 4; ++r) o[r] = f2bf_s(acc[i][j][r] + bv[j]);
        *(s4v*)&C[((size_t)bb * D_DIM + gn) * S_LEN + ssb] = o;
      }
    }
    return;
  }

  // EPI_BIAS / EPI_SCORES: LDS transpose -> coalesced 16B row stores.
  short* TB = SMEM;                 // 4 waves x 2176 shorts (32 rows x stride 68)
  const int wbase = w * 2176;
  float csum[4] = {0.f, 0.f, 0.f, 0.f};

#pragma unroll
  for (int ph = 0; ph < 2; ++ph) {
    __syncthreads();
#pragma unroll
    for (int ii = 0; ii < 2; ++ii) {
      const int i = ph * 2 + ii;
#pragma unroll
      for (int j = 0; j < 4; ++j) {
        const int gn = n0 + wn + j * 16 + l16;
#pragma unroll
        for (int r = 0; r < 4; ++r) {
          short o;
          if (EPI == EPI_SCORES) {
            const int gm = m0 + wm + i * 16 + quad * 4 + r;
            const float f = (gm >= gn) ? (__expf(acc[i][j][r] * SCALE_F) - 1.0f) : 0.0f;
            csum[j] += f;
            o = f2bf_s(f);
          } else {
            o = f2bf_s(acc[i][j][r] + bv[j]);
          }
          TB[wbase + (ii * 16 + quad * 4 + r) * 68 + j * 16 + l16] = o;
        }
      }
    }
    __syncthreads();
#pragma unroll
    for (int p = 0; p < 4; ++p) {
      const int row = p * 8 + (lane >> 3);   // 0..31
      const int cg  = lane & 7;
      const s8v vv = *(const s8v*)&TB[wbase + row * 68 + cg * 8];
      const int gm = m0 + wm + ph * 32 + row;
      const int gn = n0 + wn + cg * 8;
      *(s8v*)&C[sCz + (size_t)gm * N + gn] = vv;
    }
  }

  if (EPI == EPI_SCORES) {
#pragma unroll
    for (int j = 0; j < 4; ++j) {
      float cs = csum[j];
      cs += __shfl_xor(cs, 16, 64);
      cs += __shfl_xor(cs, 32, 64);
      if (quad == 0) atomicAdd(&Z[(bz << 11) + n0 + wn + j * 16 + l16], cs);
    }
  }
}

// scores-F kernel: 1-D grid 544 (=8x68, XCD-bijective swizzle), tri tiles.
__global__ __launch_bounds__(256, 2) void gemm_scoresF(
    const short* __restrict__ A, const short* __restrict__ B, short* __restrict__ C,
    float* __restrict__ Z)
{
  __shared__ __align__(16) short SMEM[32768];   // 64 KB
  const int bid = blockIdx.x;
  const int bsw = (bid & 7) * 68 + (bid >> 3);  // consecutive bsw share one XCD
  const int bz  = bsw / 136;
  const int t   = bsw - bz * 136;
  int ti = (int)((sqrtf(8.0f * t + 1.0f) - 1.0f) * 0.5f);
  while ((ti + 1) * (ti + 2) / 2 <= t) ++ti;
  while (ti * (ti + 1) / 2 > t) --ti;
  const int tj = t - ti * (ti + 1) / 2;         // tj <= ti
  gemm_core<EPI_SCORES>(A + (size_t)bz * S_LEN * D_DIM, B + (size_t)bz * S_LEN * D_DIM,
                        C, nullptr, SMEM, S_LEN, D_DIM,
                        (size_t)bz * S_LEN * S_LEN, ti * 128, tj * 128, bz, Z);
}

// projections: 1-D grid 768 (=8x96, XCD-bijective swizzle), z from id.
__global__ __launch_bounds__(256, 2) void proj3(
    const short* __restrict__ a0, const short* __restrict__ a1, const short* __restrict__ a2,
    const short* __restrict__ b0, const short* __restrict__ b1, const short* __restrict__ b2,
    short* __restrict__ c0, short* __restrict__ c1, short* __restrict__ c2,
    const float* __restrict__ x0, const float* __restrict__ x1, const float* __restrict__ x2)
{
  __shared__ __align__(16) short SMEM[32768];   // 64 KB
  const int bid = blockIdx.x;
  const int bsw = (bid & 7) * 96 + (bid >> 3);
  const int z   = bsw >> 8;
  const int rem = bsw & 255;
  const int m0  = (rem >> 2) * 128;
  const int n0  = (rem & 3) * 128;
  const short* A = (z == 0) ? a0 : (z == 1) ? a1 : a2;
  const short* B = (z == 0) ? b0 : (z == 1) ? b1 : b2;
  short*       C = (z == 0) ? c0 : (z == 1) ? c1 : c2;
  const float* bias = (z == 0) ? x0 : (z == 1) ? x1 : x2;
  if (z == 2)
    gemm_core<EPI_BIAS_T>(A, B, C, bias, SMEM, D_DIM, D_DIM, 0, m0, n0, 0, nullptr);
  else
    gemm_core<EPI_BIAS>(A, B, C, bias, SMEM, D_DIM, D_DIM, 0, m0, n0, 0, nullptr);
}

// out = F @ vpT'^T + T, 64x128 tiles, BK=64, K truncated at m0+64,
// triple-buffered (72 KB), prefetch distance 2 issued AFTER the barrier.
// Grid 512 1-D: h -> n0=(h&3)*128, bz=(h>>2)&3, zs=h>>4; co-resident pairs
// (h, h+256) get complementary niter (sum 33); long blocks dispatch first.
__global__ __launch_bounds__(256, 2) void gemm_outF(
    const short* __restrict__ F, const short* __restrict__ vpT,
    const float* __restrict__ Tv, float* __restrict__ out)
{
  __shared__ __align__(16) short SMEM[36864];   // 72 KB

  const int tid  = threadIdx.x;
  const int h    = blockIdx.x;
  const int n0   = (h & 3) * 128;
  const int bz   = (h >> 2) & 3;
  const int zs   = h >> 4;                      // 0..31
  const int mi   = (zs < 16) ? (31 - zs) : (zs - 16);
  const int m0   = mi * 64;

  const short* A = F   + (size_t)bz * S_LEN * S_LEN;
  const short* B = vpT + (size_t)bz * D_DIM * S_LEN;

  const int w    = tid >> 6;
  const int lane = tid & 63;
  const int quad = lane >> 4;
  const int l16  = lane & 15;
  const int wm   = (w >> 1) * 32;
  const int wn   = (w & 1) * 64;

  const int strow = tid >> 3;
  const int gl = ((tid & 7) ^ (strow & 7)) * 8;

  f4v acc[2][4];
#pragma unroll
  for (int i = 0; i < 2; ++i)
#pragma unroll
    for (int j = 0; j < 4; ++j)
#pragma unroll
      for (int r = 0; r < 4; ++r) acc[i][j][r] = 0.0f;

  const short* Ag = A + (size_t)(m0 + strow) * S_LEN + gl;
  const short* Bg = B + (size_t)(n0 + strow) * S_LEN + gl;
  const size_t pstr = (size_t)32 * S_LEN;
  const int t8 = tid * 8;
  const int swq = l16 & 7;

  const unsigned base = lds_addr(SMEM);
  unsigned aoff[2], boff[4];
#pragma unroll
  for (int ii = 0; ii < 2; ++ii)
    aoff[ii] = base + (unsigned)((wm + ii * 16 + l16) * 128 + ((quad ^ swq) * 16));
#pragma unroll
  for (int j = 0; j < 4; ++j)
    boff[j] = base + 8192u + (unsigned)((wn + j * 16 + l16) * 128 + ((quad ^ swq) * 16));

  const int niter = mi + 1;   // K runs 0 .. m0+64

  // preload tiles 0,1 into bufs 0,1 (6 loads each: A x2, B x4)
#pragma unroll
  for (int pre = 0; pre < 2; ++pre) {
    short* dst = SMEM + pre * 12288 + t8;
    const int k0 = pre << 6;
#pragma unroll
    for (int p = 0; p < 2; ++p) glds16(Ag + k0 + p * pstr, dst + p * 2048);
#pragma unroll
    for (int p = 0; p < 4; ++p) glds16(Bg + k0 + p * pstr, dst + 4096 + p * 2048);
  }

  int cbuf = 0;
  for (int i = 0; i < niter; ++i) {
    if (i + 1 < niter) { WAITV(6); } else { WAITV(0); }   // tile i landed
    SBAR();
    SCHEDB();

    if (i + 2 < niter) {          // issue i+2 into the buffer read at i-1
      int nb = cbuf + 2; if (nb >= 3) nb -= 3;
      const int k2 = (i + 2) << 6;
      short* dst = SMEM + nb * 12288 + t8;
#pragma unroll
      for (int p = 0; p < 2; ++p) glds16(Ag + k2 + p * pstr, dst + p * 2048);
#pragma unroll
      for (int p = 0; p < 4; ++p) glds16(Bg + k2 + p * pstr, dst + 4096 + p * 2048);
      SCHEDB();
    }

    const unsigned cofs = (unsigned)(cbuf * 24576);
    cbuf = (cbuf == 2) ? 0 : cbuf + 1;
#pragma unroll
    for (int kk = 0; kk < 2; ++kk) {
      const unsigned kx = (unsigned)(kk << 6);
      s8v af[2], bf[4];
#pragma unroll
      for (int ii = 0; ii < 2; ++ii) af[ii] = dsr128((aoff[ii] ^ kx) + cofs);
#pragma unroll
      for (int j = 0; j < 4; ++j)   bf[j]  = dsr128((boff[j] ^ kx) + cofs);
      WAITL0();
      SCHEDB();
      __builtin_amdgcn_s_setprio(1);
#pragma unroll
      for (int ii = 0; ii < 2; ++ii)
#pragma unroll
        for (int j = 0; j < 4; ++j)
          acc[ii][j] = __builtin_amdgcn_mfma_f32_16x16x32_bf16(af[ii], bf[j], acc[ii][j], 0, 0, 0);
      __builtin_amdgcn_s_setprio(0);
    }
  }

  float* Cf = out + (size_t)bz * S_LEN * D_DIM;
#pragma unroll
  for (int i = 0; i < 2; ++i) {
#pragma unroll
    for (int j = 0; j < 4; ++j) {
      const int gn = n0 + wn + j * 16 + l16;
      const float tvn = Tv[(bz << 9) + gn];
#pragma unroll
      for (int r = 0; r < 4; ++r) {
        const int gm = m0 + wm + i * 16 + quad * 4 + r;
        Cf[(size_t)gm * D_DIM + gn] = acc[i][j][r] + tvn;
      }
    }
  }
}

// fp32 -> bf16, one launch for data (x<2048) and weights (x>=2048).
__global__ __launch_bounds__(256) void cvt_all(
    const float* __restrict__ q, const float* __restrict__ k, const float* __restrict__ v,
    const float* __restrict__ wq, const float* __restrict__ wk, const float* __restrict__ wv,
    short* __restrict__ qb, short* __restrict__ Wqb)
{
  const int y = blockIdx.y;
  const float* s; short* d; int i;
  if (blockIdx.x < 2048) {
    s = (y == 0) ? q : (y == 1) ? k : v;
    d = qb + (size_t)y * 4194304;
    i = (blockIdx.x * 256 + threadIdx.x) * 8;
  } else {
    s = (y == 0) ? wq : (y == 1) ? wk : wv;
    d = Wqb + (size_t)y * 262144;
    i = ((int)(blockIdx.x - 2048) * 256 + threadIdx.x) * 8;
  }
  const float4 f0 = *(const float4*)(s + i);
  const float4 f1 = *(const float4*)(s + i + 4);
  s8v o;
  o[0] = f2bf_s(f0.x); o[1] = f2bf_s(f0.y); o[2] = f2bf_s(f0.z); o[3] = f2bf_s(f0.w);
  o[4] = f2bf_s(f1.x); o[5] = f2bf_s(f1.y); o[6] = f2bf_s(f1.z); o[7] = f2bf_s(f1.w);
  *(s8v*)(d + i) = o;
}

// block per (b,d): vpT[b][d][k] /= (2048+ZF[b][k]); Tv[b,d] = sum_k (fp32)
__global__ __launch_bounds__(256) void scale_vpt_T(
    short* __restrict__ vpT, const float* __restrict__ ZF, float* __restrict__ Tv)
{
  __shared__ float red[4];
  const int b = blockIdx.y, d = blockIdx.x, tid = threadIdx.x;
  const size_t rowbase = ((size_t)(b * D_DIM + d)) * S_LEN;
  const float* zf = ZF + (b << 11);
  const int k0 = tid * 8;

  s8v v = *(s8v*)&vpT[rowbase + k0];
  float s = 0.0f;
#pragma unroll
  for (int i = 0; i < 8; ++i) {
    const float w = bf2f_s(v[i]) / (2048.0f + zf[k0 + i]);
    s += w;
    v[i] = f2bf_s(w);
  }
  *(s8v*)&vpT[rowbase + k0] = v;

#pragma unroll
  for (int off = 32; off >= 1; off >>= 1) s += __shfl_xor(s, off, 64);
  if ((tid & 63) == 0) red[tid >> 6] = s;
  __syncthreads();
  if (tid == 0) Tv[(b << 9) + d] = red[0] + red[1] + red[2] + red[3];
}

extern "C" void kernel_launch(void* const* d_in, const int* in_sizes, int n_in,
                              void* d_out, int out_size, void* d_ws, size_t ws_size,
                              hipStream_t stream) {
  const float* q   = (const float*)d_in[0];
  const float* k   = (const float*)d_in[1];
  const float* v   = (const float*)d_in[2];
  const float* WQw = (const float*)d_in[3];
  const float* WQb = (const float*)d_in[4];
  const float* WKw = (const float*)d_in[5];
  const float* WKb = (const float*)d_in[6];
  const float* WVw = (const float*)d_in[7];
  const float* WVb = (const float*)d_in[8];

  char* ws = (char*)d_ws;
  // F occupies [0,32M); bf16 input/weight copies alias its head (dead before F written)
  short* F   = (short*)(ws);                 // 32 MB  [4][2048][2048] (lower tiles only)
  short* qb  = (short*)(ws);                 //  8 MB  (qb,kb,vb contiguous)
  short* Wqb = (short*)(ws + 25165824);      // 3x 512 KB contiguous
  short* qp  = (short*)(ws + 33554432);      //  8 MB  [4][2048][512]
  short* kp  = (short*)(ws + 41943040);      //  8 MB
  short* vpT = (short*)(ws + 50331648);      //  8 MB  [4][512][2048]
  float* ZF  = (float*)(ws + 58720256);      // 32 KB  [4][2048]
  float* Tv  = (float*)(ws + 58753024);      //  8 KB  [4][512]
  short* kb  = qb + 4194304;
  short* vb  = qb + 8388608;
  short* Wkb = Wqb + 262144;
  short* Wvb = Wqb + 524288;

  const dim3 blk(256);

  (void)hipMemsetAsync(ZF, 0, 4 * S_LEN * sizeof(float), stream);

  cvt_all<<<dim3(2176, 3), blk, 0, stream>>>(q, k, v, WQw, WKw, WVw, qb, Wqb);

  // projections: M=8192, N=512, K=512 — 768 blocks, XCD-swizzled in-kernel
  proj3<<<dim3(768), blk, 0, stream>>>(
      qb, kb, vb, Wqb, Wkb, Wvb, qp, kp, vpT, WQb, WKb, WVb);

  // F = expm1(scale*qp@kp^T) lower-tri tiles + fused ZF colsum: 544 blocks
  gemm_scoresF<<<dim3(544), blk, 0, stream>>>(qp, kp, F, ZF);

  // vpT' = vpT/(2048+ZF); Tv = rowsum(vpT')
  scale_vpt_T<<<dim3(512, 4), blk, 0, stream>>>(vpT, ZF, Tv);

  // out = F @ vpT'^T + Tv: 64x128 tiles, K truncated at m0+64, balanced pairs
  gemm_outF<<<dim3(512), blk, 0, stream>>>(F, vpT, Tv, (float*)d_out);
}